// Round 22
// baseline (309.840 us; speedup 1.0000x reference)
//
#include <hip/hip_runtime.h>
#include <math.h>

#define TT   8192
#define HH   768
#define FF   3072
#define NEXP 8
#define NP   16384          // T*K pairs
#define BM   128            // N-tile cols
#define BM1  256            // M-tile rows
#define MTP1 72             // padded 256-row tile count (div 8)
#define ESTR (FF*HH)

typedef unsigned short u16;
typedef __attribute__((ext_vector_type(8))) short bf16x8;
typedef __attribute__((ext_vector_type(4))) float f32x4;

__device__ __forceinline__ u16 f2b(float f) {
  unsigned u = __float_as_uint(f);
  unsigned r = (u + 0x7FFFu + ((u >> 16) & 1u)) >> 16;   // RNE
  return (u16)r;
}

__device__ __forceinline__ float b2f(u16 b) {
  return __uint_as_float(((unsigned)b) << 16);
}

// tanh-form GELU via hw exp + fast rcp; |err vs exact erf-GELU| < 1.5e-3 abs.
__device__ __forceinline__ float gelu_fast(float v) {
  float u  = v * (0.7978845608f + 0.0356774081f * v * v);
  float ex = __expf(2.0f * u);
  float th = 1.0f - 2.0f * __builtin_amdgcn_rcpf(ex + 1.0f);
  return 0.5f * v * (1.0f + th);
}

__device__ __forceinline__ float gelu_exact(float v) {
  return 0.5f * v * (1.0f + erff(v * 0.70710678118654752f));
}

__device__ __forceinline__ void gll16(const void* g, void* l) {
  __builtin_amdgcn_global_load_lds(
      (const __attribute__((address_space(1))) void*)g,
      (__attribute__((address_space(3))) void*)l, 16, 0, 0);
}

// ---------------- routing (single block) ----------------
// hdr ints: [0..7] counts, [9] tt256, [16..23] offs, [352..16735] ptok,
// [16736..33119] pwt(f32), [33120..49503] inv,
// [49504..49575] tile_e256, [49576..49647] tile_m256
__global__ __launch_bounds__(1024)
void route_all(const int* __restrict__ te, const float* __restrict__ tw,
               int* __restrict__ hdr) {
  __shared__ int cnt[NEXP], cur[NEXP];
  const int tid = threadIdx.x;
  const int lane = tid & 63, wave = tid >> 6;
  if (tid < NEXP) cnt[tid] = 0;
  __syncthreads();
  for (int base = wave * 64; base < NP; base += 1024) {
    int e = te[base + lane];
#pragma unroll
    for (int x = 0; x < NEXP; ++x) {
      unsigned long long m = __ballot(e == x);
      if (lane == 0 && m) atomicAdd(&cnt[x], __popcll(m));
    }
  }
  __syncthreads();
  if (tid == 0) {
    int run = 0, t2 = 0;
#pragma unroll
    for (int x = 0; x < NEXP; ++x) {
      cur[x] = run;
      hdr[x] = cnt[x]; hdr[16 + x] = run;
      run += cnt[x];
    }
    for (int x = 0; x < NEXP; ++x) {
      int n2 = (cnt[x] + BM1 - 1) >> 8;
      for (int i = 0; i < n2; ++i) { hdr[49504 + t2] = x; hdr[49576 + t2] = i * BM1; ++t2; }
    }
    hdr[9] = t2;
  }
  __syncthreads();
  for (int base = wave * 64; base < NP; base += 1024) {
    int i = base + lane;
    int e = te[i];
    float w = tw[i];
    int slot = 0;
#pragma unroll
    for (int x = 0; x < NEXP; ++x) {
      unsigned long long m = __ballot(e == x);
      int nb = __popcll(m);
      int below = __popcll(m & ((1ull << lane) - 1ull));
      int b = 0;
      if (lane == 0) b = nb ? atomicAdd(&cur[x], nb) : 0;
      b = __shfl(b, 0);
      if (e == x) slot = b + below;
    }
    hdr[352 + slot] = i >> 1;
    ((float*)(hdr + 16736))[slot] = w;
    hdr[33120 + i] = slot;
  }
}

// ---------------- merged convert (x then w1) ----------------
__global__ void cvt_all(const float* __restrict__ x, const float* __restrict__ w1,
                        u16* __restrict__ dst, int xn4, int totn4) {
  for (int i = blockIdx.x * 256 + threadIdx.x; i < totn4; i += gridDim.x * 256) {
    float4 v = (i < xn4) ? ((const float4*)x)[i] : ((const float4*)w1)[i - xn4];
    ushort4 o;
    o.x = f2b(v.x); o.y = f2b(v.y); o.z = f2b(v.z); o.w = f2b(v.w);
    ((ushort4*)dst)[i] = o;
  }
}

// w2 [E][F][H] f32 -> w2t [E][H][F] bf16
__global__ void transpose_w2(const float* __restrict__ w2, u16* __restrict__ w2t) {
  __shared__ u16 t[64][65];
  int e = blockIdx.z;
  int f0 = blockIdx.x * 64, h0 = blockIdx.y * 64;
  int tid = threadIdx.x;
  int tx = tid & 15, ty = tid >> 4;
  const float* s = w2 + (size_t)e * ESTR;
#pragma unroll
  for (int j = 0; j < 4; ++j) {
    int f = f0 + ty + 16 * j;
    float4 v = *(const float4*)&s[(size_t)f * HH + h0 + tx * 4];
    t[ty + 16 * j][tx * 4 + 0] = f2b(v.x);
    t[ty + 16 * j][tx * 4 + 1] = f2b(v.y);
    t[ty + 16 * j][tx * 4 + 2] = f2b(v.z);
    t[ty + 16 * j][tx * 4 + 3] = f2b(v.w);
  }
  __syncthreads();
  u16* d = w2t + (size_t)e * ESTR;
#pragma unroll
  for (int j = 0; j < 4; ++j) {
    int hr = ty + 16 * j;
    ushort4 o;
    o.x = t[tx * 4 + 0][hr];
    o.y = t[tx * 4 + 1][hr];
    o.z = t[tx * 4 + 2][hr];
    o.w = t[tx * 4 + 3][hr];
    *(ushort4*)&d[(size_t)(h0 + hr) * FF + f0 + tx * 4] = o;
  }
}

__global__ void bias_init(float* __restrict__ out, const float* __restrict__ bias) {
  int i = blockIdx.x * 256 + threadIdx.x;
  if (i < TT * HH / 4)
    ((float4*)out)[i] = ((const float4*)bias)[i % (HH / 4)];
}

// ---------------- combine (part is bf16) ----------------
__global__ void combine(const u16* __restrict__ part, const int* __restrict__ hdr,
                        const float* __restrict__ bias, float* __restrict__ out) {
  int t = blockIdx.x;
  int c = threadIdx.x;                    // 192 threads, 4 cols each
  const int* inv = hdr + 33120;
  const float* pw = (const float*)(hdr + 16736);
  int g0 = inv[2 * t], g1 = inv[2 * t + 1];
  float w0 = pw[g0], w1 = pw[g1];
  ushort4 p0 = ((const ushort4*)(part + (size_t)g0 * HH))[c];
  ushort4 p1 = ((const ushort4*)(part + (size_t)g1 * HH))[c];
  float4 b  = ((const float4*)bias)[c];
  float4 o;
  o.x = b.x + w0 * b2f(p0.x) + w1 * b2f(p1.x);
  o.y = b.y + w0 * b2f(p0.y) + w1 * b2f(p1.y);
  o.z = b.z + w0 * b2f(p0.z) + w1 * b2f(p1.z);
  o.w = b.w + w0 * b2f(p0.w) + w1 * b2f(p1.w);
  ((float4*)(out + (size_t)t * HH))[c] = o;
}

// ---------------- unified grouped GEMM, 256x128 tile, 8 waves, 2-buf ----------
// PHASE 1: h[slot] = gelu(Xg @ w1[e].T)   A gathered via ptok, AST=HH, NK=24
// PHASE 2: part[slot] = Hg @ w2t[e]       A by slot, AST=FF, NK=96
// R22 probe: 2-buffer LDS (48 KB -> 3 blocks/CU, +50% TLP) with 1-deep
// prefetch and per-iter vmcnt(0) drain (trades T4 counted-vmcnt for
// occupancy; the last untested {depth x occupancy} quadrant at this tile).
// STG issued AFTER the fragment ds_reads (R18: before = -7%).
template <int PHASE, int NT, int G>
__global__ __launch_bounds__(512, 4)
void moe_gemm(const u16* __restrict__ Asrc, const u16* __restrict__ Bsrc,
              u16* __restrict__ Outp, const int* __restrict__ hdr) {
  constexpr int KEXT = (PHASE == 1) ? HH : FF;
  constexpr int AST  = (PHASE == 1) ? HH : FF;
  constexpr int BST  = (PHASE == 1) ? HH : FF;
  constexpr int OST  = (PHASE == 1) ? FF : HH;
  constexpr int NK   = KEXT / 32;           // 24 or 96 (even)

  const int nwg = NT * MTP1;
  const int bid = blockIdx.x;
  const int l   = (bid & 7) * (nwg >> 3) + (bid >> 3);
  const int mtl = l % G;
  const int nt  = (l / G) % NT;
  const int sg  = l / (G * NT);
  const int mt  = sg * G + mtl;
  if (mt >= hdr[9]) return;

  const int e   = hdr[49504 + mt];
  const int m0  = hdr[49576 + mt];
  const int cnt = hdr[e];
  const int off = hdr[16 + e];
  const int* ptok = hdr + 352;

  __shared__ u16 Al[2][8192];   // [256][32] x 2 = 32 KB
  __shared__ u16 Bl[2][4096];   // [128][32] x 2 = 16 KB

  const int tid  = threadIdx.x;
  const int lane = tid & 63;
  const int wave = tid >> 6;
  const int wm = wave >> 1, wn = wave & 1;   // 4x2 waves, wave tile 64x64
  const int lr = lane & 15;

  const int kcs = (((tid & 3) ^ ((tid >> 3) & 3)) * 8);
  const u16* aptr[2];
#pragma unroll
  for (int i = 0; i < 2; ++i) {
    int r = (tid >> 2) + 128 * i;
    int g = off + m0 + r; g = g < NP ? g : NP - 1;
    if (PHASE == 1)
      aptr[i] = Asrc + (size_t)ptok[g] * AST + kcs;
    else
      aptr[i] = Asrc + (size_t)g * AST + kcs;
  }
  const u16* bptr = Bsrc + (size_t)e * ESTR +
                    (size_t)(nt * BM + (tid >> 2)) * BST + kcs;

  f32x4 acc[4][4] = {};
  const int pcs = (((lane >> 4) ^ ((lane >> 1) & 3)) * 8);

#define STG(BS, T) do {                                   \
    gll16(aptr[0] + (T) * 32, &Al[BS][tid * 8]);          \
    gll16(aptr[1] + (T) * 32, &Al[BS][tid * 8 + 4096]);   \
    gll16(bptr + (T) * 32, &Bl[BS][tid * 8]);             \
  } while (0)

// iter: own tile-t loads landed (vmcnt 0) -> barrier (all waves' stages
// visible, all prior reads of the stage-target buffer drained) ->
// ds_read frags -> stage t+1 into buf^1 -> lgkm drain -> 16 MFMA.
#define ITER(BC, BS, TSTG, DOST) do {                                        \
    asm volatile("s_waitcnt vmcnt(0)" ::: "memory");                         \
    __builtin_amdgcn_sched_barrier(0);                                       \
    __builtin_amdgcn_s_barrier();                                            \
    bf16x8 af[4], bfr[4];                                                    \
    _Pragma("unroll")                                                        \
    for (int i = 0; i < 4; ++i)                                              \
      af[i] = *(const bf16x8*)&Al[BC][(wm * 64 + i * 16 + lr) * 32 + pcs];   \
    _Pragma("unroll")                                                        \
    for (int i = 0; i < 4; ++i)                                              \
      bfr[i] = *(const bf16x8*)&Bl[BC][(wn * 64 + i * 16 + lr) * 32 + pcs];  \
    if (DOST) STG(BS, TSTG);                                                 \
    asm volatile("s_waitcnt lgkmcnt(0)" ::: "memory");                       \
    __builtin_amdgcn_sched_barrier(0);                                       \
    __builtin_amdgcn_s_setprio(1);                                           \
    _Pragma("unroll")                                                        \
    for (int mi = 0; mi < 4; ++mi)                                           \
      _Pragma("unroll")                                                      \
      for (int ni = 0; ni < 4; ++ni)                                         \
        acc[mi][ni] = __builtin_amdgcn_mfma_f32_16x16x32_bf16(               \
            af[mi], bfr[ni], acc[mi][ni], 0, 0, 0);                          \
    __builtin_amdgcn_s_setprio(0);                                           \
  } while (0)

  STG(0, 0);

  for (int g = 0; g < NK / 2 - 1; ++g) {
    ITER(0, 1, 2 * g + 1, 1);
    ITER(1, 0, 2 * g + 2, 1);
  }
  ITER(0, 1, NK - 1, 1);   // t = NK-2, stages last tile
  ITER(1, 0, 0, 0);        // t = NK-1, no stage
#undef ITER
#undef STG

#pragma unroll
  for (int mi = 0; mi < 4; ++mi)
#pragma unroll
    for (int ni = 0; ni < 4; ++ni)
#pragma unroll
      for (int j = 0; j < 4; ++j) {
        int rl = wm * 64 + mi * 16 + (lane >> 4) * 4 + j;
        int gr = m0 + rl;
        if (gr < cnt) {
          int col = nt * BM + wn * 64 + ni * 16 + lr;
          float v = acc[mi][ni][j];
          if (PHASE == 1) v = gelu_fast(v);
          Outp[(size_t)(off + gr) * OST + col] = f2b(v);
        }
      }
}

// ---------------- naive fallback ----------------
__global__ void naive_pair(const float* __restrict__ x, const float* __restrict__ tw,
                           const int* __restrict__ te, const float* __restrict__ w1,
                           const float* __restrict__ w2, float* __restrict__ out) {
  __shared__ float xs[HH];
  __shared__ float hb[FF];
  int t = blockIdx.x >> 1, k = blockIdx.x & 1;
  int e = te[t * 2 + k];
  float wt = tw[t * 2 + k];
  for (int i = threadIdx.x; i < HH; i += 256) xs[i] = x[(size_t)t * HH + i];
  __syncthreads();
  const float* W1 = w1 + (size_t)e * ESTR;
  for (int f = threadIdx.x; f < FF; f += 256) {
    float s = 0.f;
    const float* r = W1 + (size_t)f * HH;
    for (int i = 0; i < HH; ++i) s += xs[i] * r[i];
    hb[f] = gelu_exact(s);
  }
  __syncthreads();
  const float* W2 = w2 + (size_t)e * ESTR;
  for (int c = threadIdx.x; c < HH; c += 256) {
    float s = 0.f;
    for (int f = 0; f < FF; ++f) s += hb[f] * W2[(size_t)f * HH + c];
    atomicAdd(&out[(size_t)t * HH + c], s * wt);
  }
}

extern "C" void kernel_launch(void* const* d_in, const int* in_sizes, int n_in,
                              void* d_out, int out_size, void* d_ws, size_t ws_size,
                              hipStream_t stream) {
  const float* x    = (const float*)d_in[0];
  const float* topw = (const float*)d_in[2];
  const int*   tope = (const int*)d_in[3];
  const float* w1   = (const float*)d_in[4];
  const float* w2   = (const float*)d_in[5];
  const float* bias = (const float*)d_in[6];
  float* out = (float*)d_out;

  char* ws = (char*)d_ws;
  const size_t HDRB   = 1u << 18;
  const size_t xb_off  = HDRB;
  const size_t xb_sz   = (size_t)TT * HH * 2;
  const size_t w1_off  = xb_off + xb_sz;
  const size_t w1_sz   = (size_t)NEXP * ESTR * 2;
  const size_t w2t_off = w1_off + w1_sz;
  const size_t w2t_sz  = w1_sz;
  const size_t h_off   = w2t_off + w2t_sz;
  const size_t h_sz    = (size_t)NP * FF * 2;
  const size_t need    = h_off + h_sz;
  // part (bf16, NP*HH*2 = 25 MB) aliases the xb/w1b region (dead after ph.1).

  if (ws_size < need) {
    bias_init<<<(TT * HH / 4 + 255) / 256, 256, 0, stream>>>(out, bias);
    naive_pair<<<NP, 256, 0, stream>>>(x, topw, tope, w1, w2, out);
    return;
  }

  int* hdr   = (int*)ws;
  u16* xb    = (u16*)(ws + xb_off);
  u16* w1b   = (u16*)(ws + w1_off);
  u16* w2t   = (u16*)(ws + w2t_off);
  u16* h     = (u16*)(ws + h_off);
  u16* part  = (u16*)(ws + xb_off);                     // aliases xb/w1b

  route_all<<<1, 1024, 0, stream>>>(tope, topw, hdr);

  const int XN4 = TT * HH / 4;
  const int TOTN4 = (TT * HH + NEXP * ESTR) / 4;
  cvt_all<<<2048, 256, 0, stream>>>(x, w1, xb, XN4, TOTN4);
  transpose_w2<<<dim3(FF / 64, HH / 64, NEXP), 256, 0, stream>>>(w2, w2t);

  // phase 1: 256x128 tiles over F (NT=24), G=8
  moe_gemm<1, 24, 8><<<24 * MTP1, 512, 0, stream>>>(xb, w1b, h, hdr);
  // phase 2: 256x128 tiles over H (NT=6), G=2
  moe_gemm<2, 6, 2><<<6 * MTP1, 512, 0, stream>>>(h, w2t, part, hdr);
  combine<<<TT, HH / 4, 0, stream>>>(part, hdr, bias, out);
}

// Round 23
// 302.597 us; speedup vs baseline: 1.0239x; 1.0239x over previous
//
#include <hip/hip_runtime.h>
#include <math.h>

#define TT   8192
#define HH   768
#define FF   3072
#define NEXP 8
#define NP   16384          // T*K pairs
#define BM   128            // N-tile cols
#define BM1  256            // M-tile rows
#define MTP1 72             // padded 256-row tile count (div 8)
#define ESTR (FF*HH)

typedef unsigned short u16;
typedef __attribute__((ext_vector_type(8))) short bf16x8;
typedef __attribute__((ext_vector_type(4))) float f32x4;

__device__ __forceinline__ u16 f2b(float f) {
  unsigned u = __float_as_uint(f);
  unsigned r = (u + 0x7FFFu + ((u >> 16) & 1u)) >> 16;   // RNE
  return (u16)r;
}

__device__ __forceinline__ float b2f(u16 b) {
  return __uint_as_float(((unsigned)b) << 16);
}

// tanh-form GELU via hw exp + fast rcp; |err vs exact erf-GELU| < 1.5e-3 abs.
__device__ __forceinline__ float gelu_fast(float v) {
  float u  = v * (0.7978845608f + 0.0356774081f * v * v);
  float ex = __expf(2.0f * u);
  float th = 1.0f - 2.0f * __builtin_amdgcn_rcpf(ex + 1.0f);
  return 0.5f * v * (1.0f + th);
}

__device__ __forceinline__ float gelu_exact(float v) {
  return 0.5f * v * (1.0f + erff(v * 0.70710678118654752f));
}

__device__ __forceinline__ void gll16(const void* g, void* l) {
  __builtin_amdgcn_global_load_lds(
      (const __attribute__((address_space(1))) void*)g,
      (__attribute__((address_space(3))) void*)l, 16, 0, 0);
}

// ---------------- routing (single block) ----------------
// hdr ints: [0..7] counts, [9] tt256, [16..23] offs, [352..16735] ptok,
// [16736..33119] pwt(f32), [33120..49503] inv,
// [49504..49575] tile_e256, [49576..49647] tile_m256
__global__ __launch_bounds__(1024)
void route_all(const int* __restrict__ te, const float* __restrict__ tw,
               int* __restrict__ hdr) {
  __shared__ int cnt[NEXP], cur[NEXP];
  const int tid = threadIdx.x;
  const int lane = tid & 63, wave = tid >> 6;
  if (tid < NEXP) cnt[tid] = 0;
  __syncthreads();
  for (int base = wave * 64; base < NP; base += 1024) {
    int e = te[base + lane];
#pragma unroll
    for (int x = 0; x < NEXP; ++x) {
      unsigned long long m = __ballot(e == x);
      if (lane == 0 && m) atomicAdd(&cnt[x], __popcll(m));
    }
  }
  __syncthreads();
  if (tid == 0) {
    int run = 0, t2 = 0;
#pragma unroll
    for (int x = 0; x < NEXP; ++x) {
      cur[x] = run;
      hdr[x] = cnt[x]; hdr[16 + x] = run;
      run += cnt[x];
    }
    for (int x = 0; x < NEXP; ++x) {
      int n2 = (cnt[x] + BM1 - 1) >> 8;
      for (int i = 0; i < n2; ++i) { hdr[49504 + t2] = x; hdr[49576 + t2] = i * BM1; ++t2; }
    }
    hdr[9] = t2;
  }
  __syncthreads();
  for (int base = wave * 64; base < NP; base += 1024) {
    int i = base + lane;
    int e = te[i];
    float w = tw[i];
    int slot = 0;
#pragma unroll
    for (int x = 0; x < NEXP; ++x) {
      unsigned long long m = __ballot(e == x);
      int nb = __popcll(m);
      int below = __popcll(m & ((1ull << lane) - 1ull));
      int b = 0;
      if (lane == 0) b = nb ? atomicAdd(&cur[x], nb) : 0;
      b = __shfl(b, 0);
      if (e == x) slot = b + below;
    }
    hdr[352 + slot] = i >> 1;
    ((float*)(hdr + 16736))[slot] = w;
    hdr[33120 + i] = slot;
  }
}

// ---------------- merged convert (x then w1) ----------------
__global__ void cvt_all(const float* __restrict__ x, const float* __restrict__ w1,
                        u16* __restrict__ dst, int xn4, int totn4) {
  for (int i = blockIdx.x * 256 + threadIdx.x; i < totn4; i += gridDim.x * 256) {
    float4 v = (i < xn4) ? ((const float4*)x)[i] : ((const float4*)w1)[i - xn4];
    ushort4 o;
    o.x = f2b(v.x); o.y = f2b(v.y); o.z = f2b(v.z); o.w = f2b(v.w);
    ((ushort4*)dst)[i] = o;
  }
}

// w2 [E][F][H] f32 -> w2t [E][H][F] bf16
__global__ void transpose_w2(const float* __restrict__ w2, u16* __restrict__ w2t) {
  __shared__ u16 t[64][65];
  int e = blockIdx.z;
  int f0 = blockIdx.x * 64, h0 = blockIdx.y * 64;
  int tid = threadIdx.x;
  int tx = tid & 15, ty = tid >> 4;
  const float* s = w2 + (size_t)e * ESTR;
#pragma unroll
  for (int j = 0; j < 4; ++j) {
    int f = f0 + ty + 16 * j;
    float4 v = *(const float4*)&s[(size_t)f * HH + h0 + tx * 4];
    t[ty + 16 * j][tx * 4 + 0] = f2b(v.x);
    t[ty + 16 * j][tx * 4 + 1] = f2b(v.y);
    t[ty + 16 * j][tx * 4 + 2] = f2b(v.z);
    t[ty + 16 * j][tx * 4 + 3] = f2b(v.w);
  }
  __syncthreads();
  u16* d = w2t + (size_t)e * ESTR;
#pragma unroll
  for (int j = 0; j < 4; ++j) {
    int hr = ty + 16 * j;
    ushort4 o;
    o.x = t[tx * 4 + 0][hr];
    o.y = t[tx * 4 + 1][hr];
    o.z = t[tx * 4 + 2][hr];
    o.w = t[tx * 4 + 3][hr];
    *(ushort4*)&d[(size_t)(h0 + hr) * FF + f0 + tx * 4] = o;
  }
}

__global__ void bias_init(float* __restrict__ out, const float* __restrict__ bias) {
  int i = blockIdx.x * 256 + threadIdx.x;
  if (i < TT * HH / 4)
    ((float4*)out)[i] = ((const float4*)bias)[i % (HH / 4)];
}

// ---------------- combine (part is bf16) ----------------
__global__ void combine(const u16* __restrict__ part, const int* __restrict__ hdr,
                        const float* __restrict__ bias, float* __restrict__ out) {
  int t = blockIdx.x;
  int c = threadIdx.x;                    // 192 threads, 4 cols each
  const int* inv = hdr + 33120;
  const float* pw = (const float*)(hdr + 16736);
  int g0 = inv[2 * t], g1 = inv[2 * t + 1];
  float w0 = pw[g0], w1 = pw[g1];
  ushort4 p0 = ((const ushort4*)(part + (size_t)g0 * HH))[c];
  ushort4 p1 = ((const ushort4*)(part + (size_t)g1 * HH))[c];
  float4 b  = ((const float4*)bias)[c];
  float4 o;
  o.x = b.x + w0 * b2f(p0.x) + w1 * b2f(p1.x);
  o.y = b.y + w0 * b2f(p0.y) + w1 * b2f(p1.y);
  o.z = b.z + w0 * b2f(p0.z) + w1 * b2f(p1.z);
  o.w = b.w + w0 * b2f(p0.w) + w1 * b2f(p1.w);
  ((float4*)(out + (size_t)t * HH))[c] = o;
}

// ---------------- unified grouped GEMM, 256x128 tile, 8 waves, 3-buf ----------
// PHASE 1: h[slot] = gelu(Xg @ w1[e].T)   A gathered via ptok, AST=HH, NK=24
// PHASE 2: part[slot] = Hg @ w2t[e]       A by slot, AST=FF, NK=96
// STG = 3 gll (A rows r, r+128; B row r), issued AFTER the fragment ds_reads
// (R18 measured: issuing before them delays the lgkm drain, -7%).
// vmcnt(3) steady (2 tiles in flight).  Measured plateau: ~120 us/phase
// (644 TF ~= m248's 2-phase grouped-GEMM ceiling).  Falsified alternatives:
// 8-phase/1-block (R17 +28us), stage-early (R18 +7%), split-K (R20 +4us),
// 2-buf drain-0 (R22 +6us/phase), B-direct-to-reg (R11 2x), 256^2 BK64 (R6).
template <int PHASE, int NT, int G>
__global__ __launch_bounds__(512, 4)
void moe_gemm(const u16* __restrict__ Asrc, const u16* __restrict__ Bsrc,
              u16* __restrict__ Outp, const int* __restrict__ hdr) {
  constexpr int KEXT = (PHASE == 1) ? HH : FF;
  constexpr int AST  = (PHASE == 1) ? HH : FF;
  constexpr int BST  = (PHASE == 1) ? HH : FF;
  constexpr int OST  = (PHASE == 1) ? FF : HH;
  constexpr int NK   = KEXT / 32;           // 24 or 96 (multiple of 3)

  const int nwg = NT * MTP1;
  const int bid = blockIdx.x;
  const int l   = (bid & 7) * (nwg >> 3) + (bid >> 3);
  const int mtl = l % G;
  const int nt  = (l / G) % NT;
  const int sg  = l / (G * NT);
  const int mt  = sg * G + mtl;
  if (mt >= hdr[9]) return;

  const int e   = hdr[49504 + mt];
  const int m0  = hdr[49576 + mt];
  const int cnt = hdr[e];
  const int off = hdr[16 + e];
  const int* ptok = hdr + 352;

  __shared__ u16 Al[3][8192];   // [256][32]
  __shared__ u16 Bl[3][4096];   // [128][32]

  const int tid  = threadIdx.x;
  const int lane = tid & 63;
  const int wave = tid >> 6;
  const int wm = wave >> 1, wn = wave & 1;   // 4x2 waves, wave tile 64x64
  const int lr = lane & 15;

  const int kcs = (((tid & 3) ^ ((tid >> 3) & 3)) * 8);
  const u16* aptr[2];
#pragma unroll
  for (int i = 0; i < 2; ++i) {
    int r = (tid >> 2) + 128 * i;
    int g = off + m0 + r; g = g < NP ? g : NP - 1;
    if (PHASE == 1)
      aptr[i] = Asrc + (size_t)ptok[g] * AST + kcs;
    else
      aptr[i] = Asrc + (size_t)g * AST + kcs;
  }
  const u16* bptr = Bsrc + (size_t)e * ESTR +
                    (size_t)(nt * BM + (tid >> 2)) * BST + kcs;

  f32x4 acc[4][4] = {};
  const int pcs = (((lane >> 4) ^ ((lane >> 1) & 3)) * 8);

#define STG(BS, T) do {                                   \
    gll16(aptr[0] + (T) * 32, &Al[BS][tid * 8]);          \
    gll16(aptr[1] + (T) * 32, &Al[BS][tid * 8 + 4096]);   \
    gll16(bptr + (T) * 32, &Bl[BS][tid * 8]);             \
  } while (0)

#define ITER(BC, BS, TSTG, DOST, VMN) do {                                   \
    asm volatile("s_waitcnt vmcnt(" #VMN ")" ::: "memory");                  \
    __builtin_amdgcn_sched_barrier(0);                                       \
    __builtin_amdgcn_s_barrier();                                            \
    bf16x8 af[4], bfr[4];                                                    \
    _Pragma("unroll")                                                        \
    for (int i = 0; i < 4; ++i)                                              \
      af[i] = *(const bf16x8*)&Al[BC][(wm * 64 + i * 16 + lr) * 32 + pcs];   \
    _Pragma("unroll")                                                        \
    for (int i = 0; i < 4; ++i)                                              \
      bfr[i] = *(const bf16x8*)&Bl[BC][(wn * 64 + i * 16 + lr) * 32 + pcs];  \
    if (DOST) STG(BS, TSTG);                                                 \
    asm volatile("s_waitcnt lgkmcnt(0)" ::: "memory");                       \
    __builtin_amdgcn_sched_barrier(0);                                       \
    __builtin_amdgcn_s_setprio(1);                                           \
    _Pragma("unroll")                                                        \
    for (int mi = 0; mi < 4; ++mi)                                           \
      _Pragma("unroll")                                                      \
      for (int ni = 0; ni < 4; ++ni)                                         \
        acc[mi][ni] = __builtin_amdgcn_mfma_f32_16x16x32_bf16(               \
            af[mi], bfr[ni], acc[mi][ni], 0, 0, 0);                          \
    __builtin_amdgcn_s_setprio(0);                                           \
  } while (0)

  STG(0, 0);
  STG(1, 1);

  for (int g = 0; g < NK / 3 - 1; ++g) {
    const int t0 = g * 3;
    ITER(0, 2, t0 + 2, 1, 3);
    ITER(1, 0, t0 + 3, 1, 3);
    ITER(2, 1, t0 + 4, 1, 3);
  }
  ITER(0, 2, NK - 1, 1, 3);
  ITER(1, 0, 0, 0, 3);
  ITER(2, 0, 0, 0, 0);
#undef ITER
#undef STG

#pragma unroll
  for (int mi = 0; mi < 4; ++mi)
#pragma unroll
    for (int ni = 0; ni < 4; ++ni)
#pragma unroll
      for (int j = 0; j < 4; ++j) {
        int rl = wm * 64 + mi * 16 + (lane >> 4) * 4 + j;
        int gr = m0 + rl;
        if (gr < cnt) {
          int col = nt * BM + wn * 64 + ni * 16 + lr;
          float v = acc[mi][ni][j];
          if (PHASE == 1) v = gelu_fast(v);
          Outp[(size_t)(off + gr) * OST + col] = f2b(v);
        }
      }
}

// ---------------- naive fallback ----------------
__global__ void naive_pair(const float* __restrict__ x, const float* __restrict__ tw,
                           const int* __restrict__ te, const float* __restrict__ w1,
                           const float* __restrict__ w2, float* __restrict__ out) {
  __shared__ float xs[HH];
  __shared__ float hb[FF];
  int t = blockIdx.x >> 1, k = blockIdx.x & 1;
  int e = te[t * 2 + k];
  float wt = tw[t * 2 + k];
  for (int i = threadIdx.x; i < HH; i += 256) xs[i] = x[(size_t)t * HH + i];
  __syncthreads();
  const float* W1 = w1 + (size_t)e * ESTR;
  for (int f = threadIdx.x; f < FF; f += 256) {
    float s = 0.f;
    const float* r = W1 + (size_t)f * HH;
    for (int i = 0; i < HH; ++i) s += xs[i] * r[i];
    hb[f] = gelu_exact(s);
  }
  __syncthreads();
  const float* W2 = w2 + (size_t)e * ESTR;
  for (int c = threadIdx.x; c < HH; c += 256) {
    float s = 0.f;
    for (int f = 0; f < FF; ++f) s += hb[f] * W2[(size_t)f * HH + c];
    atomicAdd(&out[(size_t)t * HH + c], s * wt);
  }
}

extern "C" void kernel_launch(void* const* d_in, const int* in_sizes, int n_in,
                              void* d_out, int out_size, void* d_ws, size_t ws_size,
                              hipStream_t stream) {
  const float* x    = (const float*)d_in[0];
  const float* topw = (const float*)d_in[2];
  const int*   tope = (const int*)d_in[3];
  const float* w1   = (const float*)d_in[4];
  const float* w2   = (const float*)d_in[5];
  const float* bias = (const float*)d_in[6];
  float* out = (float*)d_out;

  char* ws = (char*)d_ws;
  const size_t HDRB   = 1u << 18;
  const size_t xb_off  = HDRB;
  const size_t xb_sz   = (size_t)TT * HH * 2;
  const size_t w1_off  = xb_off + xb_sz;
  const size_t w1_sz   = (size_t)NEXP * ESTR * 2;
  const size_t w2t_off = w1_off + w1_sz;
  const size_t w2t_sz  = w1_sz;
  const size_t h_off   = w2t_off + w2t_sz;
  const size_t h_sz    = (size_t)NP * FF * 2;
  const size_t need    = h_off + h_sz;
  // part (bf16, NP*HH*2 = 25 MB) aliases the xb/w1b region (dead after ph.1).

  if (ws_size < need) {
    bias_init<<<(TT * HH / 4 + 255) / 256, 256, 0, stream>>>(out, bias);
    naive_pair<<<NP, 256, 0, stream>>>(x, topw, tope, w1, w2, out);
    return;
  }

  int* hdr   = (int*)ws;
  u16* xb    = (u16*)(ws + xb_off);
  u16* w1b   = (u16*)(ws + w1_off);
  u16* w2t   = (u16*)(ws + w2t_off);
  u16* h     = (u16*)(ws + h_off);
  u16* part  = (u16*)(ws + xb_off);                     // aliases xb/w1b

  route_all<<<1, 1024, 0, stream>>>(tope, topw, hdr);

  const int XN4 = TT * HH / 4;
  const int TOTN4 = (TT * HH + NEXP * ESTR) / 4;
  cvt_all<<<2048, 256, 0, stream>>>(x, w1, xb, XN4, TOTN4);
  transpose_w2<<<dim3(FF / 64, HH / 64, NEXP), 256, 0, stream>>>(w2, w2t);

  // phase 1: 256x128 tiles over F (NT=24), G=8
  moe_gemm<1, 24, 8><<<24 * MTP1, 512, 0, stream>>>(xb, w1b, h, hdr);
  // phase 2: 256x128 tiles over H (NT=6), G=2
  moe_gemm<2, 6, 2><<<6 * MTP1, 512, 0, stream>>>(h, w2t, part, hdr);
  combine<<<TT, HH / 4, 0, stream>>>(part, hdr, bias, out);
}